// Round 1
// baseline (130.627 us; speedup 1.0000x reference)
//
#include <hip/hip_runtime.h>
#include <hip/hip_bf16.h>

// GRU cell, fully fused, bf16 MFMA (16x16x32), fp32 in/out.
// B=65536, D=U=256.
//
// ws layout: wzr bf16 [512][512] (Wz;Uz | Wr;Ur)^T, then whh bf16 [256][512] (Wh;Uh)^T.
// d_out doubles as scratch for r (packed bf16, wave-private layout) before final h overwrites it.

typedef __attribute__((ext_vector_type(8))) short s8v;           // 8 bf16 (as shorts) = 4 VGPR
typedef __attribute__((ext_vector_type(8))) unsigned short us8;
typedef __attribute__((ext_vector_type(4))) float f32x4;
typedef __attribute__((ext_vector_type(4))) float f4v;
typedef __attribute__((ext_vector_type(4))) unsigned int u4v;

__device__ __forceinline__ float bf2f(unsigned short u) {
  union { unsigned int i; float f; } c; c.i = ((unsigned int)u) << 16; return c.f;
}
__device__ __forceinline__ unsigned short f2bf(float f) {
  union { float f; unsigned int i; } c; c.f = f;
  return (unsigned short)((c.i + 0x7fffu + ((c.i >> 16) & 1u)) >> 16);  // RNE
}
__device__ __forceinline__ unsigned int pack2(float lo, float hi) {
  return (unsigned int)f2bf(lo) | ((unsigned int)f2bf(hi) << 16);
}
__device__ __forceinline__ float sig_(float s)  { return 1.0f / (1.0f + __expf(-s)); }
__device__ __forceinline__ float tanh_(float s) { return 2.0f / (1.0f + __expf(-2.0f * s)) - 1.0f; }

// ---------------- weight prep: fp32 [K][N] -> bf16 [N][K] concatenated ----------------
__global__ void gru_prep(const float* __restrict__ Wz, const float* __restrict__ Uz,
                         const float* __restrict__ Wr, const float* __restrict__ Ur,
                         const float* __restrict__ Wh, const float* __restrict__ Uh,
                         unsigned short* __restrict__ wzr, unsigned short* __restrict__ whh) {
  int idx = blockIdx.x * 256 + threadIdx.x;
  if (idx < 512 * 512) {
    int n = idx >> 9, k = idx & 511;
    int nn = n & 255;
    float v;
    if (n < 256) v = (k < 256) ? Wz[k * 256 + nn] : Uz[(k - 256) * 256 + nn];
    else         v = (k < 256) ? Wr[k * 256 + nn] : Ur[(k - 256) * 256 + nn];
    wzr[idx] = f2bf(v);
  } else if (idx < 512 * 512 + 256 * 512) {
    int j = idx - 512 * 512;
    int n = j >> 9, k = j & 511;
    float v = (k < 256) ? Wh[k * 256 + n] : Uh[(k - 256) * 256 + n];
    whh[j] = f2bf(v);
  }
}

// ---------------- one GEMM pass over K=512 (16 steps of 32) ----------------
// PASS 0: A=[x|h], B=(Wz;Uz)^T   -> acc = xz+hz
// PASS 1: A=[x|h], B=(Wr;Ur)^T   -> acc = xr+hr
// PASS 2: A=[x|rh],B=(Wh;Uh)^T   -> acc = xh+(r*h)Uh   (rh staged from d_out r-words)
template<int PASS>
__device__ __forceinline__ void kloop(
    f32x4 acc[4][4],
    const unsigned short* __restrict__ Bsrc,
    const unsigned int* __restrict__ outw,
    unsigned short* x_l, unsigned short* h_l, unsigned short* Bs, unsigned short* As,
    int tid, int lane, int wr, int wc, int blk)
{
  const int bn  = tid >> 1;        // 0..255 : B row (n)
  const int bkh = tid & 1;         // k-half (16 elems)
  const unsigned short* bsrc = Bsrc + bn * 512 + bkh * 16;
  unsigned short* bdst = Bs + bn * 40 + bkh * 16;

  const int ar  = tid >> 2;        // 0..127 : As row (PASS2 rh staging)
  const int akh = tid & 3;         // k-eighth (8 elems)

  const int l15 = lane & 15;
  const int lg4 = lane >> 4;

#pragma unroll
  for (int fa = 0; fa < 4; ++fa)
#pragma unroll
    for (int fb = 0; fb < 4; ++fb)
      acc[fa][fb] = (f32x4){0.f, 0.f, 0.f, 0.f};

  // prologue: stage B chunk for kc=0 (A kc=0 comes from resident x_l)
  {
    u4v b0 = *(const u4v*)(bsrc);
    u4v b1 = *(const u4v*)(bsrc + 8);
    *(u4v*)(bdst) = b0;
    *(u4v*)(bdst + 8) = b1;
  }
  __syncthreads();

  for (int kc = 0; kc < 16; ++kc) {
    // ---- issue global loads for kc+1 (hidden under MFMA below)
    u4v nb0, nb1, nr0, nr1;
    const bool hasnext = (kc < 15);
    const int kn = kc + 1;
    if (hasnext) {
      nb0 = *(const u4v*)(bsrc + kn * 32);
      nb1 = *(const u4v*)(bsrc + kn * 32 + 8);
      if (PASS == 2 && kn >= 8) {
        int col0 = (kn - 8) * 32 + akh * 8;
        unsigned int idx = (unsigned int)blk * 32768u
                         + (unsigned int)((((ar >> 6) << 2) | (col0 >> 6))) * 2048u
                         + (unsigned int)(((((ar >> 4) & 3) << 2) | ((col0 >> 4) & 3))) * 128u
                         + (unsigned int)(((ar >> 1) & 1)) * 64u
                         + (unsigned int)((ar >> 2) & 3) * 16u
                         + (unsigned int)(col0 & 15);
        nr0 = *(const u4v*)(outw + idx);
        nr1 = *(const u4v*)(outw + idx + 4);
      }
    }

    // ---- fragments + MFMA for kc
    s8v bfr[4];
#pragma unroll
    for (int fb = 0; fb < 4; ++fb)
      bfr[fb] = *(const s8v*)(Bs + (wc * 64 + fb * 16 + l15) * 40 + lg4 * 8);

    s8v afr[4];
    if (PASS == 2 && kc >= 8) {
#pragma unroll
      for (int fa = 0; fa < 4; ++fa)
        afr[fa] = *(const s8v*)(As + (wr * 64 + fa * 16 + l15) * 40 + lg4 * 8);
    } else {
      const unsigned short* abase = (kc < 8) ? x_l : h_l;
      const int gbase = (kc & 7) * 4 + lg4;     // granule (16B) index within row
#pragma unroll
      for (int fa = 0; fa < 4; ++fa) {
        int row = wr * 64 + fa * 16 + l15;
        int gs = gbase ^ (row & 7);             // bank swizzle (matches staging)
        afr[fa] = *(const s8v*)(abase + row * 256 + gs * 8);
      }
    }

#pragma unroll
    for (int fa = 0; fa < 4; ++fa)
#pragma unroll
      for (int fb = 0; fb < 4; ++fb)
        acc[fa][fb] = __builtin_amdgcn_mfma_f32_16x16x32_bf16(afr[fa], bfr[fb], acc[fa][fb], 0, 0, 0);

    __syncthreads();   // all reads of staged kc done

    // ---- write staged data for kc+1
    if (hasnext) {
      *(u4v*)(bdst) = nb0;
      *(u4v*)(bdst + 8) = nb1;
      if (PASS == 2 && kn >= 8) {
        int col0 = (kn - 8) * 32 + akh * 8;
        int gs = (col0 >> 3) ^ (ar & 7);
        s8v hh = *(const s8v*)(h_l + ar * 256 + gs * 8);
        const int half = ar & 1;
        us8 o;
#pragma unroll
        for (int j = 0; j < 4; ++j) {
          unsigned int u = nr0[j];
          unsigned short rb = half ? (unsigned short)(u >> 16) : (unsigned short)(u & 0xffffu);
          o[j] = f2bf(bf2f(rb) * bf2f((unsigned short)hh[j]));
        }
#pragma unroll
        for (int j = 0; j < 4; ++j) {
          unsigned int u = nr1[j];
          unsigned short rb = half ? (unsigned short)(u >> 16) : (unsigned short)(u & 0xffffu);
          o[4 + j] = f2bf(bf2f(rb) * bf2f((unsigned short)hh[4 + j]));
        }
        *(us8*)(As + ar * 40 + akh * 8) = o;
      }
    }
    __syncthreads();
  }
}

// ---------------- main fused kernel ----------------
__global__ __launch_bounds__(512, 2) void gru_main(
    const float* __restrict__ x, const float* __restrict__ hp,
    const unsigned short* __restrict__ wzr, const unsigned short* __restrict__ whh,
    const float* __restrict__ bz, const float* __restrict__ br, const float* __restrict__ bh,
    float* __restrict__ out)
{
  __shared__ __align__(16) unsigned short x_l[128 * 256];   // 64 KB, granule-swizzled
  __shared__ __align__(16) unsigned short h_l[128 * 256];   // 64 KB
  __shared__ __align__(16) unsigned short Bs[256 * 40];     // 20 KB, +pad rows
  __shared__ __align__(16) unsigned short As[128 * 40];     // 10 KB, +pad rows (PASS2 rh)

  const int tid = threadIdx.x;
  const int lane = tid & 63;
  const int wv = tid >> 6;
  const int wr = wv >> 2, wc = wv & 3;        // 2 x 4 wave grid; wave tile 64x64
  const int blk = blockIdx.x;
  const int row0 = blk * 128;
  const int l15 = lane & 15, lg4 = lane >> 4;

  unsigned int* outw = (unsigned int*)out;

  // ---- stage x, h tiles to LDS (fp32 -> bf16), read from HBM exactly once
  {
    const int srow = tid >> 2;     // 0..127
    const int part = tid & 3;
    const float* xs = x  + (size_t)(row0 + srow) * 256 + part * 64;
    const float* hs = hp + (size_t)(row0 + srow) * 256 + part * 64;
    unsigned short* xd = x_l + srow * 256;
    unsigned short* hd = h_l + srow * 256;
    const int r7 = srow & 7;
#pragma unroll
    for (int j = 0; j < 8; ++j) {
      f4v v0 = *(const f4v*)(xs + j * 8);
      f4v v1 = *(const f4v*)(xs + j * 8 + 4);
      int gs = (part * 8 + j) ^ r7;
      us8 o;
      o[0]=f2bf(v0[0]); o[1]=f2bf(v0[1]); o[2]=f2bf(v0[2]); o[3]=f2bf(v0[3]);
      o[4]=f2bf(v1[0]); o[5]=f2bf(v1[1]); o[6]=f2bf(v1[2]); o[7]=f2bf(v1[3]);
      *(us8*)(xd + gs * 8) = o;
    }
#pragma unroll
    for (int j = 0; j < 8; ++j) {
      f4v v0 = *(const f4v*)(hs + j * 8);
      f4v v1 = *(const f4v*)(hs + j * 8 + 4);
      int gs = (part * 8 + j) ^ r7;
      us8 o;
      o[0]=f2bf(v0[0]); o[1]=f2bf(v0[1]); o[2]=f2bf(v0[2]); o[3]=f2bf(v0[3]);
      o[4]=f2bf(v1[0]); o[5]=f2bf(v1[1]); o[6]=f2bf(v1[2]); o[7]=f2bf(v1[3]);
      *(us8*)(hd + gs * 8) = o;
    }
  }
  __syncthreads();

  f32x4 acc[4][4];
  unsigned int zreg[4][4][2];   // z gate, packed bf16 pairs, stays in registers
  float bv[4];

  // ===== PASS 0: z = sigmoid(x Wz + h Uz + bz)
  kloop<0>(acc, wzr, outw, x_l, h_l, Bs, As, tid, lane, wr, wc, blk);
#pragma unroll
  for (int fb = 0; fb < 4; ++fb) bv[fb] = bz[wc * 64 + fb * 16 + l15];
#pragma unroll
  for (int fa = 0; fa < 4; ++fa)
#pragma unroll
    for (int fb = 0; fb < 4; ++fb) {
      f32x4 a = acc[fa][fb];
      zreg[fa][fb][0] = pack2(sig_(a[0] + bv[fb]), sig_(a[1] + bv[fb]));
      zreg[fa][fb][1] = pack2(sig_(a[2] + bv[fb]), sig_(a[3] + bv[fb]));
    }

  // ===== PASS 1: r = sigmoid(x Wr + h Ur + br) -> d_out scratch (wave-private packed layout)
  kloop<1>(acc, wzr + 256 * 512, outw, x_l, h_l, Bs, As, tid, lane, wr, wc, blk);
#pragma unroll
  for (int fb = 0; fb < 4; ++fb) bv[fb] = br[wc * 64 + fb * 16 + l15];
  {
    unsigned int rbase = (unsigned int)blk * 32768u + (unsigned int)wv * 2048u + (unsigned int)lane;
#pragma unroll
    for (int fa = 0; fa < 4; ++fa)
#pragma unroll
      for (int fb = 0; fb < 4; ++fb) {
        f32x4 a = acc[fa][fb];
        outw[rbase + (fa * 4 + fb) * 128]      = pack2(sig_(a[0] + bv[fb]), sig_(a[1] + bv[fb]));
        outw[rbase + (fa * 4 + fb) * 128 + 64] = pack2(sig_(a[2] + bv[fb]), sig_(a[3] + bv[fb]));
      }
  }
  // visibility of r-words: kloop<2>'s prologue __syncthreads drains vmcnt; same-CU L1/L2 coherent

  // ===== PASS 2: h_hat = tanh(x Wh + (r*h) Uh + bh);  h = z*h + (1-z)*h_hat
  kloop<2>(acc, whh, outw, x_l, h_l, Bs, As, tid, lane, wr, wc, blk);
#pragma unroll
  for (int fb = 0; fb < 4; ++fb) bv[fb] = bh[wc * 64 + fb * 16 + l15];
#pragma unroll
  for (int fa = 0; fa < 4; ++fa) {
    const int rowl = wr * 64 + fa * 16 + lg4 * 4;
#pragma unroll
    for (int fb = 0; fb < 4; ++fb) {
      const int col = wc * 64 + fb * 16 + l15;
      f32x4 a = acc[fa][fb];
#pragma unroll
      for (int i = 0; i < 4; ++i) {
        float hhat = tanh_(a[i] + bv[fb]);
        unsigned int zw = zreg[fa][fb][i >> 1];
        float z = bf2f((unsigned short)((i & 1) ? (zw >> 16) : (zw & 0xffffu)));
        int r = rowl + i;
        int gs = (col >> 3) ^ (r & 7);
        float hpe = bf2f(h_l[r * 256 + gs * 8 + (col & 7)]);
        out[(size_t)(row0 + r) * 256 + col] = z * hpe + (1.0f - z) * hhat;
      }
    }
  }
}

extern "C" void kernel_launch(void* const* d_in, const int* in_sizes, int n_in,
                              void* d_out, int out_size, void* d_ws, size_t ws_size,
                              hipStream_t stream) {
  const float* x  = (const float*)d_in[0];
  const float* hp = (const float*)d_in[1];
  const float* Wz = (const float*)d_in[2];
  const float* Uz = (const float*)d_in[3];
  const float* bz = (const float*)d_in[4];
  const float* Wr = (const float*)d_in[5];
  const float* Ur = (const float*)d_in[6];
  const float* br = (const float*)d_in[7];
  const float* Wh = (const float*)d_in[8];
  const float* Uh = (const float*)d_in[9];
  const float* bh = (const float*)d_in[10];

  if (ws_size < (size_t)(512 * 512 + 256 * 512) * sizeof(unsigned short)) return;  // need 768 KB

  unsigned short* wzr = (unsigned short*)d_ws;
  unsigned short* whh = wzr + 512 * 512;

  gru_prep<<<1536, 256, 0, stream>>>(Wz, Uz, Wr, Ur, Wh, Uh, wzr, whh);
  gru_main<<<512, 512, 0, stream>>>(x, hp, wzr, whh, bz, br, bh, (float*)d_out);
}